// Round 1
// baseline (865.284 us; speedup 1.0000x reference)
//
#include <hip/hip_runtime.h>

#define MARGIN  0.3f
#define NEG_INF -1e30f
#define POS_INF  1e30f

#define BM 128
#define BN 128
#define BK 16

// ---- order-preserving float <-> uint mapping for atomic max/min ----
__device__ __forceinline__ unsigned f2ord(float f) {
    unsigned u = __float_as_uint(f);
    return (u & 0x80000000u) ? ~u : (u | 0x80000000u);
}
__device__ __forceinline__ float ord2f(unsigned u) {
    unsigned b = (u & 0x80000000u) ? (u ^ 0x80000000u) : ~u;
    return __uint_as_float(b);
}

// ---- kernel 1: per-row sum of squares + init ap/an accumulators ----
__global__ void sq_init_kernel(const float* __restrict__ X, int d,
                               float* __restrict__ sq,
                               unsigned* __restrict__ apk,
                               unsigned* __restrict__ ank) {
    int row = blockIdx.x;
    const float4* xr = (const float4*)(X + (size_t)row * d);
    int nv = d >> 2;
    float s = 0.f;
    for (int c = threadIdx.x; c < nv; c += blockDim.x) {
        float4 v = xr[c];
        s += v.x * v.x + v.y * v.y + v.z * v.z + v.w * v.w;
    }
    for (int off = 32; off; off >>= 1) s += __shfl_down(s, off);
    __shared__ float ws[4];
    int lane = threadIdx.x & 63, wid = threadIdx.x >> 6;
    if (lane == 0) ws[wid] = s;
    __syncthreads();
    if (threadIdx.x == 0) {
        sq[row] = ws[0] + ws[1] + ws[2] + ws[3];
        apk[row] = f2ord(NEG_INF);
        ank[row] = f2ord(POS_INF);
    }
}

// ---- kernel 2: fused Gram-tile + hardest-pos/neg mining ----
__global__ __launch_bounds__(256)
void tile_kernel(const float* __restrict__ X, const int* __restrict__ tgt,
                 const float* __restrict__ sq,
                 unsigned* __restrict__ apk, unsigned* __restrict__ ank,
                 int n, int d) {
    __shared__ float As[BK][BM];
    __shared__ float Bs[BK][BN];
    __shared__ float srow[BM], scol[BN];
    __shared__ int   trow[BM], tcol[BN];

    const int bi = blockIdx.y, bj = blockIdx.x;
    const int row0 = bi * BM, col0 = bj * BN;
    const int tid = threadIdx.x;
    const int tx = tid & 15, ty = tid >> 4;

    if (tid < BM)      { srow[tid] = sq[row0 + tid];       trow[tid] = tgt[row0 + tid]; }
    else               { int j = tid - BM; scol[j] = sq[col0 + j]; tcol[j] = tgt[col0 + j]; }

    float acc[8][8];
#pragma unroll
    for (int r = 0; r < 8; r++)
#pragma unroll
        for (int c = 0; c < 8; c++) acc[r][c] = 0.f;

    for (int k0 = 0; k0 < d; k0 += BK) {
        __syncthreads();
#pragma unroll
        for (int h = 0; h < 2; h++) {
            int q = tid + 256 * h;      // 512 float4 slots per tile side
            int m = q >> 2, cg = q & 3; // row in tile, 4-col group
            float4 va = *(const float4*)(X + (size_t)(row0 + m) * d + k0 + cg * 4);
            As[cg * 4 + 0][m] = va.x; As[cg * 4 + 1][m] = va.y;
            As[cg * 4 + 2][m] = va.z; As[cg * 4 + 3][m] = va.w;
            float4 vb = *(const float4*)(X + (size_t)(col0 + m) * d + k0 + cg * 4);
            Bs[cg * 4 + 0][m] = vb.x; Bs[cg * 4 + 1][m] = vb.y;
            Bs[cg * 4 + 2][m] = vb.z; Bs[cg * 4 + 3][m] = vb.w;
        }
        __syncthreads();
#pragma unroll
        for (int k = 0; k < BK; k++) {
            float a[8], b[8];
#pragma unroll
            for (int r = 0; r < 8; r++) a[r] = As[k][ty * 8 + r];
            // split cols into two 4-wide groups at stride 64 -> <=2-way bank alias (free)
#pragma unroll
            for (int c = 0; c < 4; c++) b[c] = Bs[k][tx * 4 + c];
#pragma unroll
            for (int c = 0; c < 4; c++) b[4 + c] = Bs[k][64 + tx * 4 + c];
#pragma unroll
            for (int r = 0; r < 8; r++)
#pragma unroll
                for (int c = 0; c < 8; c++)
                    acc[r][c] = fmaf(a[r], b[c], acc[r][c]);
        }
    }

    // ---- epilogue: dist = sq_i + sq_j - 2*ip ; mine hardest pos/neg ----
    float ap[8], an[8];
#pragma unroll
    for (int r = 0; r < 8; r++) { ap[r] = NEG_INF; an[r] = POS_INF; }
#pragma unroll
    for (int r = 0; r < 8; r++) {
        int mi = ty * 8 + r;
        float si = srow[mi];
        int   ti = trow[mi];
#pragma unroll
        for (int c = 0; c < 8; c++) {
            int mj = (c < 4) ? (tx * 4 + c) : (64 + tx * 4 + (c - 4));
            float dist = si + scol[mj] - 2.0f * acc[r][c];
            bool same = (ti == tcol[mj]);
            ap[r] = fmaxf(ap[r], same ? dist : NEG_INF);
            an[r] = fminf(an[r], same ? POS_INF : dist);
        }
    }
    // reduce across the 16 tx-lanes (consecutive lanes within the wave)
#pragma unroll
    for (int r = 0; r < 8; r++) {
#pragma unroll
        for (int off = 1; off < 16; off <<= 1) {
            ap[r] = fmaxf(ap[r], __shfl_xor(ap[r], off));
            an[r] = fminf(an[r], __shfl_xor(an[r], off));
        }
    }
    if (tx == 0) {
#pragma unroll
        for (int r = 0; r < 8; r++) {
            int gi = row0 + ty * 8 + r;
            atomicMax(&apk[gi], f2ord(ap[r]));
            atomicMin(&ank[gi], f2ord(an[r]));
        }
    }
}

// ---- kernel 3: loss = mean(relu(ap - an + margin)) ----
__global__ void loss_kernel(const unsigned* __restrict__ apk,
                            const unsigned* __restrict__ ank,
                            float* __restrict__ out, int n) {
    float s = 0.f;
    for (int i = threadIdx.x; i < n; i += blockDim.x) {
        float ap = ord2f(apk[i]);
        float an = ord2f(ank[i]);
        s += fmaxf(ap - an + MARGIN, 0.0f);
    }
    for (int off = 32; off; off >>= 1) s += __shfl_down(s, off);
    __shared__ float ws[4];
    int lane = threadIdx.x & 63, wid = threadIdx.x >> 6;
    if (lane == 0) ws[wid] = s;
    __syncthreads();
    if (threadIdx.x == 0) out[0] = (ws[0] + ws[1] + ws[2] + ws[3]) / (float)n;
}

extern "C" void kernel_launch(void* const* d_in, const int* in_sizes, int n_in,
                              void* d_out, int out_size, void* d_ws, size_t ws_size,
                              hipStream_t stream) {
    const float* X   = (const float*)d_in[0];
    const int*   tgt = (const int*)d_in[1];
    const int n = in_sizes[1];
    const int d = in_sizes[0] / n;

    float*    sq  = (float*)d_ws;
    unsigned* apk = (unsigned*)((char*)d_ws + (size_t)n * sizeof(float));
    unsigned* ank = apk + n;

    sq_init_kernel<<<n, 256, 0, stream>>>(X, d, sq, apk, ank);
    dim3 grid(n / BN, n / BM);
    tile_kernel<<<grid, 256, 0, stream>>>(X, tgt, sq, apk, ank, n, d);
    loss_kernel<<<1, 256, 0, stream>>>(apk, ank, (float*)d_out, n);
}

// Round 2
// 423.285 us; speedup vs baseline: 2.0442x; 2.0442x over previous
//
#include <hip/hip_runtime.h>
#include <hip/hip_bf16.h>

#define MARGIN  0.3f
#define NEG_INF -1e30f
#define POS_INF  1e30f

#define BMN 128
#define BK  64
#define NTH 256

typedef __attribute__((ext_vector_type(8))) short bf16x8;
typedef __attribute__((ext_vector_type(4))) float f32x4;

// ---- order-preserving float <-> uint mapping for atomic max/min ----
__device__ __forceinline__ unsigned f2ord(float f) {
    unsigned u = __float_as_uint(f);
    return (u & 0x80000000u) ? ~u : (u | 0x80000000u);
}
__device__ __forceinline__ float ord2f(unsigned u) {
    unsigned b = (u & 0x80000000u) ? (u ^ 0x80000000u) : ~u;
    return __uint_as_float(b);
}

// fp32 pair -> packed bf16 (RNE)
__device__ __forceinline__ unsigned short f2bf(float f) {
    unsigned u = __float_as_uint(f);
    u += 0x7fffu + ((u >> 16) & 1u);
    return (unsigned short)(u >> 16);
}
__device__ __forceinline__ unsigned pk_bf16(float lo, float hi) {
    return (unsigned)f2bf(lo) | ((unsigned)f2bf(hi) << 16);
}

// ---- kernel 1: per-row sum of squares + init ap/an accumulators ----
__global__ void sq_init_kernel(const float* __restrict__ X, int d,
                               float* __restrict__ sq,
                               unsigned* __restrict__ apk,
                               unsigned* __restrict__ ank) {
    int row = blockIdx.x;
    const float4* xr = (const float4*)(X + (size_t)row * d);
    int nv = d >> 2;
    float s = 0.f;
    for (int c = threadIdx.x; c < nv; c += blockDim.x) {
        float4 v = xr[c];
        s += v.x * v.x + v.y * v.y + v.z * v.z + v.w * v.w;
    }
    for (int off = 32; off; off >>= 1) s += __shfl_down(s, off);
    __shared__ float ws[4];
    int lane = threadIdx.x & 63, wid = threadIdx.x >> 6;
    if (lane == 0) ws[wid] = s;
    __syncthreads();
    if (threadIdx.x == 0) {
        sq[row] = ws[0] + ws[1] + ws[2] + ws[3];
        apk[row] = f2ord(NEG_INF);
        ank[row] = f2ord(POS_INF);
    }
}

// ---- kernel 2: MFMA Gram tile (upper-tri blocks) + row&col mining ----
__global__ __launch_bounds__(NTH)
void mfma_tile_kernel(const float* __restrict__ X, const int* __restrict__ tgt,
                      const float* __restrict__ sq,
                      unsigned* __restrict__ apk, unsigned* __restrict__ ank,
                      int n, int d) {
    __shared__ short As[BMN * BK];           // 16 KB, XOR-swizzled
    __shared__ short Bs[BMN * BK];           // 16 KB
    __shared__ float srow_s[BMN], scol_s[BMN];
    __shared__ int   trow_s[BMN], tcol_s[BMN];

    const int nt = n / BMN;
    // XCD-bijective swizzle: total blocks = nt*(nt+1)/2 = 528, 528 % 8 == 0
    const int total = nt * (nt + 1) / 2;
    const int cpx = total / 8;
    int b = (blockIdx.x % 8) * cpx + blockIdx.x / 8;
    // map linear upper-tri index -> (bi, bj)
    int bi = 0, rem = b;
    for (; bi < nt; ++bi) { int cnt = nt - bi; if (rem < cnt) break; rem -= cnt; }
    const int bj = bi + rem;
    const int row0 = bi * BMN, col0 = bj * BMN;

    const int tid  = threadIdx.x;
    const int lane = tid & 63, wid = tid >> 6;
    const int wr = wid >> 1, wc = wid & 1;      // 2x2 waves, each 64x64
    const int lr = lane & 15, lh = lane >> 4;

    if (tid < BMN) { srow_s[tid] = sq[row0 + tid]; trow_s[tid] = tgt[row0 + tid]; }
    else { int j = tid - BMN; scol_s[j] = sq[col0 + j]; tcol_s[j] = tgt[col0 + j]; }

    f32x4 acc[4][4];
#pragma unroll
    for (int m = 0; m < 4; ++m)
#pragma unroll
        for (int nn = 0; nn < 4; ++nn) acc[m][nn] = (f32x4){0.f, 0.f, 0.f, 0.f};

    for (int k0 = 0; k0 < d; k0 += BK) {
        __syncthreads();
        // stage A (rows row0..) and B (rows col0..): fp32 -> bf16, swizzled LDS
#pragma unroll
        for (int h = 0; h < 8; ++h) {
            int q = tid + NTH * h;            // 0..2047
            int row = q >> 4, cg = q & 15;    // 16 float4 groups per 64-col row
            float4 v = *(const float4*)(X + (size_t)(row0 + row) * d + k0 + cg * 4);
            uint2 w; w.x = pk_bf16(v.x, v.y); w.y = pk_bf16(v.z, v.w);
            int byte = row * 128 + ((cg * 8) ^ ((row & 7) << 4));
            *(uint2*)((char*)As + byte) = w;
        }
#pragma unroll
        for (int h = 0; h < 8; ++h) {
            int q = tid + NTH * h;
            int row = q >> 4, cg = q & 15;
            float4 v = *(const float4*)(X + (size_t)(col0 + row) * d + k0 + cg * 4);
            uint2 w; w.x = pk_bf16(v.x, v.y); w.y = pk_bf16(v.z, v.w);
            int byte = row * 128 + ((cg * 8) ^ ((row & 7) << 4));
            *(uint2*)((char*)Bs + byte) = w;
        }
        __syncthreads();
#pragma unroll
        for (int kk = 0; kk < 2; ++kk) {
            bf16x8 af[4], bfr[4];
            const int kb2 = (kk * 32 + lh * 8) * 2;   // byte offset along k
#pragma unroll
            for (int m = 0; m < 4; ++m) {
                int ar = wr * 64 + m * 16 + lr;
                af[m] = *(bf16x8*)((char*)As + ar * 128 + (kb2 ^ ((ar & 7) << 4)));
            }
#pragma unroll
            for (int nn = 0; nn < 4; ++nn) {
                int br = wc * 64 + nn * 16 + lr;
                bfr[nn] = *(bf16x8*)((char*)Bs + br * 128 + (kb2 ^ ((br & 7) << 4)));
            }
#pragma unroll
            for (int m = 0; m < 4; ++m)
#pragma unroll
                for (int nn = 0; nn < 4; ++nn)
                    acc[m][nn] = __builtin_amdgcn_mfma_f32_16x16x32_bf16(
                        af[m], bfr[nn], acc[m][nn], 0, 0, 0);
        }
    }

    // ---- epilogue: dist = sq_i + sq_j - 2*ip; mine rows AND cols ----
    float sc[4]; int tc[4];
#pragma unroll
    for (int nn = 0; nn < 4; ++nn) {
        int cl = wc * 64 + nn * 16 + lr;
        sc[nn] = scol_s[cl]; tc[nn] = tcol_s[cl];
    }
    float rap[4][4], ran[4][4], cap[4], can[4];
#pragma unroll
    for (int nn = 0; nn < 4; ++nn) { cap[nn] = NEG_INF; can[nn] = POS_INF; }
#pragma unroll
    for (int m = 0; m < 4; ++m)
#pragma unroll
        for (int j = 0; j < 4; ++j) { rap[m][j] = NEG_INF; ran[m][j] = POS_INF; }

#pragma unroll
    for (int m = 0; m < 4; ++m) {
#pragma unroll
        for (int j = 0; j < 4; ++j) {
            int rl = wr * 64 + m * 16 + lh * 4 + j;
            float sr = srow_s[rl];
            int   tr = trow_s[rl];
#pragma unroll
            for (int nn = 0; nn < 4; ++nn) {
                float dist = sr + sc[nn] - 2.0f * acc[m][nn][j];
                bool same = (tr == tc[nn]);
                float apv = same ? dist : NEG_INF;
                float anv = same ? POS_INF : dist;
                rap[m][j] = fmaxf(rap[m][j], apv);
                ran[m][j] = fminf(ran[m][j], anv);
                cap[nn]   = fmaxf(cap[nn], apv);
                can[nn]   = fminf(can[nn], anv);
            }
        }
    }
    // row mining: reduce over cols (lane bits 0..3), atomic per row
#pragma unroll
    for (int m = 0; m < 4; ++m) {
#pragma unroll
        for (int j = 0; j < 4; ++j) {
            float a = rap[m][j], v = ran[m][j];
#pragma unroll
            for (int off = 1; off < 16; off <<= 1) {
                a = fmaxf(a, __shfl_xor(a, off));
                v = fminf(v, __shfl_xor(v, off));
            }
            if (lr == 0) {
                int gr = row0 + wr * 64 + m * 16 + lh * 4 + j;
                atomicMax(&apk[gr], f2ord(a));
                atomicMin(&ank[gr], f2ord(v));
            }
        }
    }
    // col mining: reduce over rows (lane bits 4..5), atomic per col
#pragma unroll
    for (int nn = 0; nn < 4; ++nn) {
        float a = cap[nn], v = can[nn];
#pragma unroll
        for (int off = 16; off < 64; off <<= 1) {
            a = fmaxf(a, __shfl_xor(a, off));
            v = fminf(v, __shfl_xor(v, off));
        }
        if (lane < 16) {
            int gc = col0 + wc * 64 + nn * 16 + lr;
            atomicMax(&apk[gc], f2ord(a));
            atomicMin(&ank[gc], f2ord(v));
        }
    }
}

// ---- kernel 3: loss = mean(relu(ap - an + margin)) ----
__global__ void loss_kernel(const unsigned* __restrict__ apk,
                            const unsigned* __restrict__ ank,
                            float* __restrict__ out, int n) {
    float s = 0.f;
    for (int i = threadIdx.x; i < n; i += blockDim.x) {
        float ap = ord2f(apk[i]);
        float an = ord2f(ank[i]);
        s += fmaxf(ap - an + MARGIN, 0.0f);
    }
    for (int off = 32; off; off >>= 1) s += __shfl_down(s, off);
    __shared__ float ws[4];
    int lane = threadIdx.x & 63, wid = threadIdx.x >> 6;
    if (lane == 0) ws[wid] = s;
    __syncthreads();
    if (threadIdx.x == 0) out[0] = (ws[0] + ws[1] + ws[2] + ws[3]) / (float)n;
}

extern "C" void kernel_launch(void* const* d_in, const int* in_sizes, int n_in,
                              void* d_out, int out_size, void* d_ws, size_t ws_size,
                              hipStream_t stream) {
    const float* X   = (const float*)d_in[0];
    const int*   tgt = (const int*)d_in[1];
    const int n = in_sizes[1];
    const int d = in_sizes[0] / n;

    float*    sq  = (float*)d_ws;
    unsigned* apk = (unsigned*)((char*)d_ws + (size_t)n * sizeof(float));
    unsigned* ank = apk + n;

    sq_init_kernel<<<n, 256, 0, stream>>>(X, d, sq, apk, ank);
    const int nt = n / BMN;
    const int total = nt * (nt + 1) / 2;   // upper-triangular block pairs
    mfma_tile_kernel<<<total, NTH, 0, stream>>>(X, tgt, sq, apk, ank, n, d);
    loss_kernel<<<1, 256, 0, stream>>>(apk, ank, (float*)d_out, n);
}

// Round 3
// 160.179 us; speedup vs baseline: 5.4020x; 2.6426x over previous
//
#include <hip/hip_runtime.h>
#include <hip/hip_bf16.h>

#define MARGIN  0.3f
#define NEG_INF -1e30f
#define POS_INF  1e30f

#define BMN 128
#define BK  64
#define NTH 256

typedef __attribute__((ext_vector_type(8))) short bf16x8;
typedef __attribute__((ext_vector_type(4))) float f32x4;

// async global->LDS, 16B per lane (dest must be linear in lane; source is per-lane)
#define GLOAD_LDS16(g, l) __builtin_amdgcn_global_load_lds(                      \
    (const __attribute__((address_space(1))) void*)(g),                          \
    (__attribute__((address_space(3))) void*)(l), 16, 0, 0)

// ---- order-preserving float <-> uint mapping for atomic max/min ----
__device__ __forceinline__ unsigned f2ord(float f) {
    unsigned u = __float_as_uint(f);
    return (u & 0x80000000u) ? ~u : (u | 0x80000000u);
}
__device__ __forceinline__ float ord2f(unsigned u) {
    unsigned b = (u & 0x80000000u) ? (u ^ 0x80000000u) : ~u;
    return __uint_as_float(b);
}
__device__ __forceinline__ unsigned short f2bf(float f) {
    unsigned u = __float_as_uint(f);
    u += 0x7fffu + ((u >> 16) & 1u);
    return (unsigned short)(u >> 16);
}

// ---- kernel 1: fp32 -> bf16 convert + row sum-of-squares + init acc ----
__global__ __launch_bounds__(256)
void convert_kernel(const float* __restrict__ X, int d,
                    unsigned short* __restrict__ Xb,
                    float* __restrict__ sq,
                    unsigned* __restrict__ apk,
                    unsigned* __restrict__ ank) {
    const int row = blockIdx.x;
    const int tid = threadIdx.x;
    const float4* xr = (const float4*)(X + (size_t)row * d);
    float4 v0 = xr[tid * 2];
    float4 v1 = xr[tid * 2 + 1];
    float s = v0.x * v0.x + v0.y * v0.y + v0.z * v0.z + v0.w * v0.w
            + v1.x * v1.x + v1.y * v1.y + v1.z * v1.z + v1.w * v1.w;
    uint4 w;
    w.x = (unsigned)f2bf(v0.x) | ((unsigned)f2bf(v0.y) << 16);
    w.y = (unsigned)f2bf(v0.z) | ((unsigned)f2bf(v0.w) << 16);
    w.z = (unsigned)f2bf(v1.x) | ((unsigned)f2bf(v1.y) << 16);
    w.w = (unsigned)f2bf(v1.z) | ((unsigned)f2bf(v1.w) << 16);
    *(uint4*)(Xb + (size_t)row * d + tid * 8) = w;

    for (int off = 32; off; off >>= 1) s += __shfl_down(s, off);
    __shared__ float ws[4];
    int lane = tid & 63, wid = tid >> 6;
    if (lane == 0) ws[wid] = s;
    __syncthreads();
    if (tid == 0) {
        sq[row] = ws[0] + ws[1] + ws[2] + ws[3];
        apk[row] = f2ord(NEG_INF);
        ank[row] = f2ord(POS_INF);
    }
}

// ---- kernel 2: MFMA Gram tile (upper-tri blocks) + row&col mining ----
__global__ __launch_bounds__(NTH)
void mfma_tile_kernel(const unsigned short* __restrict__ Xb,
                      const int* __restrict__ tgt,
                      const float* __restrict__ sq,
                      unsigned* __restrict__ apk, unsigned* __restrict__ ank,
                      int n, int d) {
    __shared__ short As[BMN * BK];           // 16 KB, XOR-swizzled image
    __shared__ short Bs[BMN * BK];           // 16 KB
    __shared__ float srow_s[BMN], scol_s[BMN];
    __shared__ int   trow_s[BMN], tcol_s[BMN];

    const int nt = n / BMN;
    const int total = nt * (nt + 1) / 2;     // 528, divisible by 8
    const int cpx = total / 8;
    int b = (blockIdx.x % 8) * cpx + blockIdx.x / 8;
    int bi = 0, rem = b;
    for (; bi < nt; ++bi) { int cnt = nt - bi; if (rem < cnt) break; rem -= cnt; }
    const int bj = bi + rem;
    const int row0 = bi * BMN, col0 = bj * BMN;

    const int tid  = threadIdx.x;
    const int lane = tid & 63, wid = tid >> 6;
    const int wr = wid >> 1, wc = wid & 1;   // 2x2 waves, each 64x64 quadrant
    const int lr = lane & 15, lh = lane >> 4;

    if (tid < BMN) { srow_s[tid] = sq[row0 + tid]; trow_s[tid] = tgt[row0 + tid]; }
    else { int j = tid - BMN; scol_s[j] = sq[col0 + j]; tcol_s[j] = tgt[col0 + j]; }

    f32x4 acc[4][4];
#pragma unroll
    for (int m = 0; m < 4; ++m)
#pragma unroll
        for (int nn = 0; nn < 4; ++nn) acc[m][nn] = (f32x4){0.f, 0.f, 0.f, 0.f};

    const size_t dstride = (size_t)d * 2;    // row stride in bytes
    const int base = wid * 1024 + lane * 16; // linear LDS dest (lane-contig)

    for (int k0 = 0; k0 < d; k0 += BK) {
        // stage A/B: async DMA, source pre-swizzled so LDS image is swizzled
#pragma unroll
        for (int it = 0; it < 4; ++it) {
            int db = it * 4096 + base;
            int r = db >> 7, kb = db & 127;
            int skb = kb ^ ((r & 7) << 4);
            GLOAD_LDS16((const char*)Xb + (size_t)(row0 + r) * dstride + k0 * 2 + skb,
                        (char*)As + db);
        }
#pragma unroll
        for (int it = 0; it < 4; ++it) {
            int db = it * 4096 + base;
            int r = db >> 7, kb = db & 127;
            int skb = kb ^ ((r & 7) << 4);
            GLOAD_LDS16((const char*)Xb + (size_t)(col0 + r) * dstride + k0 * 2 + skb,
                        (char*)Bs + db);
        }
        __syncthreads();   // drains vmcnt + lgkm (m97 structure)
#pragma unroll
        for (int kk = 0; kk < 2; ++kk) {
            bf16x8 af[4], bfr[4];
            const int kb2 = kk * 64 + lh * 16;       // byte offset along k
#pragma unroll
            for (int m = 0; m < 4; ++m) {
                int ar = wr * 64 + m * 16 + lr;
                af[m] = *(bf16x8*)((char*)As + ar * 128 + (kb2 ^ ((ar & 7) << 4)));
            }
#pragma unroll
            for (int nn = 0; nn < 4; ++nn) {
                int br = wc * 64 + nn * 16 + lr;
                bfr[nn] = *(bf16x8*)((char*)Bs + br * 128 + (kb2 ^ ((br & 7) << 4)));
            }
#pragma unroll
            for (int m = 0; m < 4; ++m)
#pragma unroll
                for (int nn = 0; nn < 4; ++nn)
                    acc[m][nn] = __builtin_amdgcn_mfma_f32_16x16x32_bf16(
                        af[m], bfr[nn], acc[m][nn], 0, 0, 0);
        }
        __syncthreads();   // LDS reads done before next stage overwrites
    }

    // ---- epilogue: dist = sq_i + sq_j - 2*ip; mine rows AND cols ----
    float sc[4]; int tc[4];
#pragma unroll
    for (int nn = 0; nn < 4; ++nn) {
        int cl = wc * 64 + nn * 16 + lr;
        sc[nn] = scol_s[cl]; tc[nn] = tcol_s[cl];
    }
    float rap[4][4], ran[4][4], cap[4], can[4];
#pragma unroll
    for (int nn = 0; nn < 4; ++nn) { cap[nn] = NEG_INF; can[nn] = POS_INF; }
#pragma unroll
    for (int m = 0; m < 4; ++m)
#pragma unroll
        for (int j = 0; j < 4; ++j) { rap[m][j] = NEG_INF; ran[m][j] = POS_INF; }

#pragma unroll
    for (int m = 0; m < 4; ++m) {
#pragma unroll
        for (int j = 0; j < 4; ++j) {
            int rl = wr * 64 + m * 16 + lh * 4 + j;
            float sr = srow_s[rl];
            int   tr = trow_s[rl];
#pragma unroll
            for (int nn = 0; nn < 4; ++nn) {
                float dist = sr + sc[nn] - 2.0f * acc[m][nn][j];
                bool same = (tr == tc[nn]);
                float apv = same ? dist : NEG_INF;
                float anv = same ? POS_INF : dist;
                rap[m][j] = fmaxf(rap[m][j], apv);
                ran[m][j] = fminf(ran[m][j], anv);
                cap[nn]   = fmaxf(cap[nn], apv);
                can[nn]   = fminf(can[nn], anv);
            }
        }
    }
    // row mining: reduce over cols (lane bits 0..3), atomic per row
#pragma unroll
    for (int m = 0; m < 4; ++m) {
#pragma unroll
        for (int j = 0; j < 4; ++j) {
            float a = rap[m][j], v = ran[m][j];
#pragma unroll
            for (int off = 1; off < 16; off <<= 1) {
                a = fmaxf(a, __shfl_xor(a, off));
                v = fminf(v, __shfl_xor(v, off));
            }
            if (lr == 0) {
                int gr = row0 + wr * 64 + m * 16 + lh * 4 + j;
                atomicMax(&apk[gr], f2ord(a));
                atomicMin(&ank[gr], f2ord(v));
            }
        }
    }
    // col mining: reduce over rows (lane bits 4..5), atomic per col
#pragma unroll
    for (int nn = 0; nn < 4; ++nn) {
        float a = cap[nn], v = can[nn];
#pragma unroll
        for (int off = 16; off < 64; off <<= 1) {
            a = fmaxf(a, __shfl_xor(a, off));
            v = fminf(v, __shfl_xor(v, off));
        }
        if (lane < 16) {
            int gc = col0 + wc * 64 + nn * 16 + lr;
            atomicMax(&apk[gc], f2ord(a));
            atomicMin(&ank[gc], f2ord(v));
        }
    }
}

// ---- kernel 3: loss = mean(relu(ap - an + margin)) ----
__global__ void loss_kernel(const unsigned* __restrict__ apk,
                            const unsigned* __restrict__ ank,
                            float* __restrict__ out, int n) {
    float s = 0.f;
    for (int i = threadIdx.x; i < n; i += blockDim.x) {
        float ap = ord2f(apk[i]);
        float an = ord2f(ank[i]);
        s += fmaxf(ap - an + MARGIN, 0.0f);
    }
    for (int off = 32; off; off >>= 1) s += __shfl_down(s, off);
    __shared__ float ws[4];
    int lane = threadIdx.x & 63, wid = threadIdx.x >> 6;
    if (lane == 0) ws[wid] = s;
    __syncthreads();
    if (threadIdx.x == 0) out[0] = (ws[0] + ws[1] + ws[2] + ws[3]) / (float)n;
}

extern "C" void kernel_launch(void* const* d_in, const int* in_sizes, int n_in,
                              void* d_out, int out_size, void* d_ws, size_t ws_size,
                              hipStream_t stream) {
    const float* X   = (const float*)d_in[0];
    const int*   tgt = (const int*)d_in[1];
    const int n = in_sizes[1];
    const int d = in_sizes[0] / n;

    float*    sq  = (float*)d_ws;
    unsigned* apk = (unsigned*)((char*)d_ws + (size_t)n * 4);
    unsigned* ank = apk + n;
    unsigned short* Xb = (unsigned short*)((char*)d_ws + (size_t)n * 12);

    convert_kernel<<<n, 256, 0, stream>>>(X, d, Xb, sq, apk, ank);
    const int nt = n / BMN;
    const int total = nt * (nt + 1) / 2;
    mfma_tile_kernel<<<total, NTH, 0, stream>>>(Xb, tgt, sq, apk, ank, n, d);
    loss_kernel<<<1, 256, 0, stream>>>(apk, ank, (float*)d_out, n);
}

// Round 4
// 154.314 us; speedup vs baseline: 5.6073x; 1.0380x over previous
//
#include <hip/hip_runtime.h>
#include <hip/hip_bf16.h>

#define MARGIN  0.3f
#define NEG_INF -1e30f
#define POS_INF  1e30f

#define BMN 128
#define BK  64
#define NTH 256

typedef __attribute__((ext_vector_type(8))) short bf16x8;
typedef __attribute__((ext_vector_type(4))) float f32x4;

// async global->LDS, 16B per lane (dest linear in lane; source is per-lane)
#define GLOAD_LDS16(g, l) __builtin_amdgcn_global_load_lds(                      \
    (const __attribute__((address_space(1))) void*)(g),                          \
    (__attribute__((address_space(3))) void*)(l), 16, 0, 0)

// ---- order-preserving float <-> uint mapping for atomic max/min ----
__device__ __forceinline__ unsigned f2ord(float f) {
    unsigned u = __float_as_uint(f);
    return (u & 0x80000000u) ? ~u : (u | 0x80000000u);
}
__device__ __forceinline__ float ord2f(unsigned u) {
    unsigned b = (u & 0x80000000u) ? (u ^ 0x80000000u) : ~u;
    return __uint_as_float(b);
}
__device__ __forceinline__ unsigned short f2bf(float f) {
    unsigned u = __float_as_uint(f);
    u += 0x7fffu + ((u >> 16) & 1u);
    return (unsigned short)(u >> 16);
}

// ---- kernel 1: fp32 -> bf16 convert + row sum-of-squares + init acc ----
__global__ __launch_bounds__(256)
void convert_kernel(const float* __restrict__ X, int d,
                    unsigned short* __restrict__ Xb,
                    float* __restrict__ sq,
                    unsigned* __restrict__ apk,
                    unsigned* __restrict__ ank) {
    const int row = blockIdx.x;
    const int tid = threadIdx.x;
    const float4* xr = (const float4*)(X + (size_t)row * d);
    float4 v0 = xr[tid * 2];
    float4 v1 = xr[tid * 2 + 1];
    float s = v0.x * v0.x + v0.y * v0.y + v0.z * v0.z + v0.w * v0.w
            + v1.x * v1.x + v1.y * v1.y + v1.z * v1.z + v1.w * v1.w;
    uint4 w;
    w.x = (unsigned)f2bf(v0.x) | ((unsigned)f2bf(v0.y) << 16);
    w.y = (unsigned)f2bf(v0.z) | ((unsigned)f2bf(v0.w) << 16);
    w.z = (unsigned)f2bf(v1.x) | ((unsigned)f2bf(v1.y) << 16);
    w.w = (unsigned)f2bf(v1.z) | ((unsigned)f2bf(v1.w) << 16);
    *(uint4*)(Xb + (size_t)row * d + tid * 8) = w;

    for (int off = 32; off; off >>= 1) s += __shfl_down(s, off);
    __shared__ float ws[4];
    int lane = tid & 63, wid = tid >> 6;
    if (lane == 0) ws[wid] = s;
    __syncthreads();
    if (tid == 0) {
        sq[row] = ws[0] + ws[1] + ws[2] + ws[3];
        apk[row] = f2ord(NEG_INF);
        ank[row] = f2ord(POS_INF);
    }
}

// ---- kernel 2: MFMA Gram tile (upper-tri blocks), 2-phase dbuf pipeline ----
__global__ __launch_bounds__(NTH)
void mfma_tile_kernel(const unsigned short* __restrict__ Xb,
                      const int* __restrict__ tgt,
                      const float* __restrict__ sq,
                      unsigned* __restrict__ apk, unsigned* __restrict__ ank,
                      int n, int d) {
    __shared__ short As[2][BMN * BK];        // 2 x 16 KB, XOR-swizzled image
    __shared__ short Bs[2][BMN * BK];        // 2 x 16 KB
    __shared__ float srow_s[BMN], scol_s[BMN];
    __shared__ int   trow_s[BMN], tcol_s[BMN];

    const int nt = n / BMN;
    const int total = nt * (nt + 1) / 2;     // 528, divisible by 8
    const int cpx = total / 8;
    int b = (blockIdx.x % 8) * cpx + blockIdx.x / 8;
    int bi = 0, rem = b;
    for (; bi < nt; ++bi) { int cnt = nt - bi; if (rem < cnt) break; rem -= cnt; }
    const int bj = bi + rem;
    const int row0 = bi * BMN, col0 = bj * BMN;

    const int tid  = threadIdx.x;
    const int lane = tid & 63, wid = tid >> 6;
    const int wr = wid >> 1, wc = wid & 1;   // 2x2 waves, each 64x64 quadrant
    const int lr = lane & 15, lh = lane >> 4;

    if (tid < BMN) { srow_s[tid] = sq[row0 + tid]; trow_s[tid] = tgt[row0 + tid]; }
    else { int j = tid - BMN; scol_s[j] = sq[col0 + j]; tcol_s[j] = tgt[col0 + j]; }

    f32x4 acc[4][4];
#pragma unroll
    for (int m = 0; m < 4; ++m)
#pragma unroll
        for (int nn = 0; nn < 4; ++nn) acc[m][nn] = (f32x4){0.f, 0.f, 0.f, 0.f};

    const size_t dstride = (size_t)d * 2;    // row stride in bytes
    const int base = wid * 1024 + lane * 16; // linear LDS dest (lane-contig)
    const char* Arow = (const char*)Xb + (size_t)row0 * dstride;
    const char* Brow = (const char*)Xb + (size_t)col0 * dstride;

#define STAGE(sel, kbyte)                                                        \
    do {                                                                         \
        _Pragma("unroll")                                                        \
        for (int it = 0; it < 4; ++it) {                                         \
            int db = it * 4096 + base;                                           \
            int r = db >> 7, kb = db & 127;                                      \
            int skb = kb ^ ((r & 7) << 4);                                       \
            GLOAD_LDS16(Arow + (size_t)r * dstride + (kbyte) + skb,              \
                        (char*)As[sel] + db);                                    \
        }                                                                        \
        _Pragma("unroll")                                                        \
        for (int it = 0; it < 4; ++it) {                                         \
            int db = it * 4096 + base;                                           \
            int r = db >> 7, kb = db & 127;                                      \
            int skb = kb ^ ((r & 7) << 4);                                       \
            GLOAD_LDS16(Brow + (size_t)r * dstride + (kbyte) + skb,              \
                        (char*)Bs[sel] + db);                                    \
        }                                                                        \
    } while (0)

    const int nt_k = d / BK;
    STAGE(0, 0);
    __syncthreads();                          // drain prologue loads
    int cur = 0;
    for (int t = 0; t < nt_k; ++t) {
        if (t + 1 < nt_k) STAGE(cur ^ 1, (t + 1) * (BK * 2));  // prefetch next
#pragma unroll
        for (int kk = 0; kk < 2; ++kk) {
            bf16x8 af[4], bfr[4];
            const int kb2 = kk * 64 + lh * 16;        // byte offset along k
#pragma unroll
            for (int m = 0; m < 4; ++m) {
                int ar = wr * 64 + m * 16 + lr;
                af[m] = *(bf16x8*)((char*)As[cur] + ar * 128 + (kb2 ^ ((ar & 7) << 4)));
            }
#pragma unroll
            for (int nn = 0; nn < 4; ++nn) {
                int br = wc * 64 + nn * 16 + lr;
                bfr[nn] = *(bf16x8*)((char*)Bs[cur] + br * 128 + (kb2 ^ ((br & 7) << 4)));
            }
#pragma unroll
            for (int m = 0; m < 4; ++m)
#pragma unroll
                for (int nn = 0; nn < 4; ++nn)
                    acc[m][nn] = __builtin_amdgcn_mfma_f32_16x16x32_bf16(
                        af[m], bfr[nn], acc[m][nn], 0, 0, 0);
        }
        __syncthreads();   // one barrier per K-step: drains prefetch + guards reuse
        cur ^= 1;
    }
#undef STAGE

    // ---- epilogue: dist = sq_i + sq_j - 2*ip; mine rows AND cols ----
    float sc[4]; int tc[4];
#pragma unroll
    for (int nn = 0; nn < 4; ++nn) {
        int cl = wc * 64 + nn * 16 + lr;
        sc[nn] = scol_s[cl]; tc[nn] = tcol_s[cl];
    }
    float rap[4][4], ran[4][4], cap[4], can[4];
#pragma unroll
    for (int nn = 0; nn < 4; ++nn) { cap[nn] = NEG_INF; can[nn] = POS_INF; }
#pragma unroll
    for (int m = 0; m < 4; ++m)
#pragma unroll
        for (int j = 0; j < 4; ++j) { rap[m][j] = NEG_INF; ran[m][j] = POS_INF; }

#pragma unroll
    for (int m = 0; m < 4; ++m) {
#pragma unroll
        for (int j = 0; j < 4; ++j) {
            int rl = wr * 64 + m * 16 + lh * 4 + j;
            float sr = srow_s[rl];
            int   tr = trow_s[rl];
#pragma unroll
            for (int nn = 0; nn < 4; ++nn) {
                float dist = sr + sc[nn] - 2.0f * acc[m][nn][j];
                bool same = (tr == tc[nn]);
                float apv = same ? dist : NEG_INF;
                float anv = same ? POS_INF : dist;
                rap[m][j] = fmaxf(rap[m][j], apv);
                ran[m][j] = fminf(ran[m][j], anv);
                cap[nn]   = fmaxf(cap[nn], apv);
                can[nn]   = fminf(can[nn], anv);
            }
        }
    }
    // row mining: reduce over cols (lane bits 0..3), atomic per row
#pragma unroll
    for (int m = 0; m < 4; ++m) {
#pragma unroll
        for (int j = 0; j < 4; ++j) {
            float a = rap[m][j], v = ran[m][j];
#pragma unroll
            for (int off = 1; off < 16; off <<= 1) {
                a = fmaxf(a, __shfl_xor(a, off));
                v = fminf(v, __shfl_xor(v, off));
            }
            if (lr == 0) {
                int gr = row0 + wr * 64 + m * 16 + lh * 4 + j;
                atomicMax(&apk[gr], f2ord(a));
                atomicMin(&ank[gr], f2ord(v));
            }
        }
    }
    // col mining: reduce over rows (lane bits 4..5), atomic per col
#pragma unroll
    for (int nn = 0; nn < 4; ++nn) {
        float a = cap[nn], v = can[nn];
#pragma unroll
        for (int off = 16; off < 64; off <<= 1) {
            a = fmaxf(a, __shfl_xor(a, off));
            v = fminf(v, __shfl_xor(v, off));
        }
        if (lane < 16) {
            int gc = col0 + wc * 64 + nn * 16 + lr;
            atomicMax(&apk[gc], f2ord(a));
            atomicMin(&ank[gc], f2ord(v));
        }
    }
}

// ---- kernel 3: loss = mean(relu(ap - an + margin)) ----
__global__ __launch_bounds__(1024)
void loss_kernel(const unsigned* __restrict__ apk,
                 const unsigned* __restrict__ ank,
                 float* __restrict__ out, int n) {
    float s = 0.f;
    for (int i = threadIdx.x; i < n; i += blockDim.x) {
        float ap = ord2f(apk[i]);
        float an = ord2f(ank[i]);
        s += fmaxf(ap - an + MARGIN, 0.0f);
    }
    for (int off = 32; off; off >>= 1) s += __shfl_down(s, off);
    __shared__ float ws[16];
    int lane = threadIdx.x & 63, wid = threadIdx.x >> 6;
    if (lane == 0) ws[wid] = s;
    __syncthreads();
    if (threadIdx.x == 0) {
        float t = 0.f;
        for (int w = 0; w < 16; ++w) t += ws[w];
        out[0] = t / (float)n;
    }
}

extern "C" void kernel_launch(void* const* d_in, const int* in_sizes, int n_in,
                              void* d_out, int out_size, void* d_ws, size_t ws_size,
                              hipStream_t stream) {
    const float* X   = (const float*)d_in[0];
    const int*   tgt = (const int*)d_in[1];
    const int n = in_sizes[1];
    const int d = in_sizes[0] / n;

    float*    sq  = (float*)d_ws;
    unsigned* apk = (unsigned*)((char*)d_ws + (size_t)n * 4);
    unsigned* ank = apk + n;
    unsigned short* Xb = (unsigned short*)((char*)d_ws + (size_t)n * 12);

    convert_kernel<<<n, 256, 0, stream>>>(X, d, Xb, sq, apk, ank);
    const int nt = n / BMN;
    const int total = nt * (nt + 1) / 2;
    mfma_tile_kernel<<<total, NTH, 0, stream>>>(Xb, tgt, sq, apk, ank, n, d);
    loss_kernel<<<1, 1024, 0, stream>>>(apk, ank, (float*)d_out, n);
}